// Round 4
// baseline (243.045 us; speedup 1.0000x reference)
//
#include <hip/hip_runtime.h>
#include <hip/hip_bf16.h>

// LocalCausalAttention: b=4, t=4096, h=16, d=64, window W=64.
// I/O f32, internal bf16 MFMA. One WG (4 waves) handles TWO consecutive
// t-blocks (jb=2bx, 2bx+1): tile1's prefetch overlaps tile0's compute, and
// tile1 reuses tile0's K/V upper half via ring indexing (XOR 64).
//   per tile: Q[64x64] @ K[128x64]^T -> band softmax -> P[64x128] @ V[128x64].

#define TT 4096
#define HH 16
#define DD 64
#define WW 64
#define NBLK (TT / WW)

typedef __attribute__((ext_vector_type(8))) short bf16x8;
typedef __attribute__((ext_vector_type(4))) float f32x4;

static __device__ __forceinline__ ushort f2bf(float x) {
    return __builtin_bit_cast(unsigned short, __float2bfloat16(x));
}
static __device__ __forceinline__ uint pack2(float a, float b) {
    return (uint)f2bf(a) | ((uint)f2bf(b) << 16);
}

__global__ __launch_bounds__(256, 3)
void lca_fwd(const float* __restrict__ q, const float* __restrict__ k,
             const float* __restrict__ v, const int* __restrict__ am,
             float* __restrict__ out)
{
    const int jb0 = 2 * blockIdx.x, jb1 = jb0 + 1;
    const int hi = blockIdx.y;
    const int bi = blockIdx.z;

    // P overlays Q + K rows 0..56. Tile1 keeps old K rows 64..127 (intact)
    // as its logical rows 0..63 via XOR-64 ring; same for sVt columns.
    __shared__ union {
        struct { ushort Q[64][72]; ushort K[128][72]; } qk;
        ushort P[64][136];
    } u;
    __shared__ ushort sVt[64][136];   // V^T [d][key-phys]
    __shared__ int    sKv[128];
    __shared__ int    sQv[64];

    const int tid = threadIdx.x;
    const size_t rowstride = (size_t)HH * DD;
    const size_t qbase0 = ((size_t)(bi * TT + jb0 * WW) * HH + hi) * DD;
    const size_t qbase1 = qbase0 + (size_t)WW * rowstride;
    const long  kstart0 = (long)jb0 * WW - WW;

    // ================= tile0 staging =================
    float4 fq[4], fk[8], fv[8];
    #pragma unroll
    for (int p = 0; p < 4; ++p) {
        int idx = p * 256 + tid;
        int row = idx >> 4, c4 = (idx & 15) * 4;
        fq[p] = *(const float4*)(q + qbase0 + (size_t)row * rowstride + c4);
    }
    if (jb0 > 0) {
        #pragma unroll
        for (int p = 0; p < 8; ++p) {
            int idx = p * 256 + tid;
            int row = idx >> 4, c4 = (idx & 15) * 4;
            fk[p] = *(const float4*)(k + ((size_t)(bi * TT + kstart0 + row) * HH + hi) * DD + c4);
        }
        #pragma unroll
        for (int p = 0; p < 8; ++p) {
            int idx = p * 256 + tid;
            int row = idx >> 4, c4 = (idx & 15) * 4;
            fv[p] = *(const float4*)(v + ((size_t)(bi * TT + kstart0 + row) * HH + hi) * DD + c4);
        }
    } else {
        #pragma unroll
        for (int p = 0; p < 8; ++p) {
            float4 z = make_float4(0.f, 0.f, 0.f, 0.f);
            if (p >= 4) {
                int idx = p * 256 + tid;
                int row = idx >> 4, c4 = (idx & 15) * 4;
                z = *(const float4*)(k + ((size_t)(bi * TT + (row - 64)) * HH + hi) * DD + c4);
            }
            fk[p] = z;
        }
        #pragma unroll
        for (int p = 0; p < 8; ++p) {
            float4 z = make_float4(0.f, 0.f, 0.f, 0.f);
            if (p >= 4) {
                int idx = p * 256 + tid;
                int row = idx >> 4, c4 = (idx & 15) * 4;
                z = *(const float4*)(v + ((size_t)(bi * TT + (row - 64)) * HH + hi) * DD + c4);
            }
            fv[p] = z;
        }
    }
    if (tid < 128) {
        long tok = kstart0 + tid;
        sKv[tid] = (tok >= 0) && (am[(size_t)bi * TT + tok] != 0);
    } else if (tid < 192) {
        int r = tid - 128;
        sQv[r] = (am[(size_t)bi * TT + jb0 * WW + r] != 0);
    }
    #pragma unroll
    for (int p = 0; p < 4; ++p) {
        int idx = p * 256 + tid;
        int row = idx >> 4, c4 = (idx & 15) * 4;
        uint2 w; w.x = pack2(fq[p].x, fq[p].y); w.y = pack2(fq[p].z, fq[p].w);
        *(uint2*)(&u.qk.Q[row][c4]) = w;
    }
    #pragma unroll
    for (int p = 0; p < 8; ++p) {
        int idx = p * 256 + tid;
        int row = idx >> 4, c4 = (idx & 15) * 4;
        uint2 w; w.x = pack2(fk[p].x, fk[p].y); w.y = pack2(fk[p].z, fk[p].w);
        *(uint2*)(&u.qk.K[row][c4]) = w;
    }
    #pragma unroll
    for (int p = 0; p < 8; ++p) {
        int idx = p * 256 + tid;
        int row = idx >> 4, c4 = (idx & 15) * 4;   // row = key, c4 = d
        sVt[c4 + 0][row] = f2bf(fv[p].x);
        sVt[c4 + 1][row] = f2bf(fv[p].y);
        sVt[c4 + 2][row] = f2bf(fv[p].z);
        sVt[c4 + 3][row] = f2bf(fv[p].w);
    }

    // ---- prefetch tile1 (only NEW 64 K/V rows + Q1), in flight over tile0 ----
    float4 gq[4], gk[4], gv[4];
    #pragma unroll
    for (int p = 0; p < 4; ++p) {
        int idx = p * 256 + tid;
        int row = idx >> 4, c4 = (idx & 15) * 4;   // row 0..63
        gq[p] = *(const float4*)(q + qbase1 + (size_t)row * rowstride + c4);
        gk[p] = *(const float4*)(k + ((size_t)(bi * TT + jb1 * WW + row) * HH + hi) * DD + c4);
        gv[p] = *(const float4*)(v + ((size_t)(bi * TT + jb1 * WW + row) * HH + hi) * DD + c4);
    }
    __syncthreads();

    const int wv = tid >> 6, lane = tid & 63;
    const int quad = lane >> 4, l15 = lane & 15;
    const int r0 = 16 * wv + quad * 4;
    const float NEG = -1.0e9f;
    const float CEXP = 0.125f * 1.44269504088896f;

    // ---- one attention tile; koff = ring offset (0 or 64) ----
    auto compute_tile = [&](int koff, size_t qb) {
        bf16x8 aq0 = *(const bf16x8*)(&u.qk.Q[16 * wv + l15][quad * 8]);
        bf16x8 aq1 = *(const bf16x8*)(&u.qk.Q[16 * wv + l15][32 + quad * 8]);
        f32x4 acc[8];
        #pragma unroll
        for (int kt = 0; kt < 8; ++kt) {
            f32x4 a = {0.f, 0.f, 0.f, 0.f};
            int pr = (16 * kt + l15) ^ koff;
            bf16x8 b0 = *(const bf16x8*)(&u.qk.K[pr][quad * 8]);
            bf16x8 b1 = *(const bf16x8*)(&u.qk.K[pr][32 + quad * 8]);
            a = __builtin_amdgcn_mfma_f32_16x16x32_bf16(aq0, b0, a, 0, 0, 0);
            a = __builtin_amdgcn_mfma_f32_16x16x32_bf16(aq1, b1, a, 0, 0, 0);
            acc[kt] = a;
        }
        __syncthreads();   // all waves done with Q/K before P overwrites them

        float rmax[4] = {NEG, NEG, NEG, NEG};
        #pragma unroll
        for (int kt = 0; kt < 8; ++kt) {
            int c = 16 * kt + l15;
            int kvc = sKv[c];
            #pragma unroll
            for (int reg = 0; reg < 4; ++reg) {
                int r = r0 + reg;
                bool valid = (c > r) && (c <= r + WW) && kvc;
                float s = valid ? acc[kt][reg] : NEG;
                acc[kt][reg] = s;
                rmax[reg] = fmaxf(rmax[reg], s);
            }
        }
        #pragma unroll
        for (int reg = 0; reg < 4; ++reg) {
            #pragma unroll
            for (int m = 1; m <= 8; m <<= 1)
                rmax[reg] = fmaxf(rmax[reg], __shfl_xor(rmax[reg], m, 64));
        }
        float rsum[4] = {0.f, 0.f, 0.f, 0.f};
        #pragma unroll
        for (int kt = 0; kt < 8; ++kt) {
            int c = 16 * kt + l15;
            #pragma unroll
            for (int reg = 0; reg < 4; ++reg) {
                float s = acc[kt][reg];
                float pex = (s > -1.0e8f) ? exp2f((s - rmax[reg]) * CEXP) : 0.f;
                rsum[reg] += pex;
                u.P[r0 + reg][c] = f2bf(pex);
            }
        }
        float rden[4];
        #pragma unroll
        for (int reg = 0; reg < 4; ++reg) {
            #pragma unroll
            for (int m = 1; m <= 8; m <<= 1)
                rsum[reg] += __shfl_xor(rsum[reg], m, 64);
            rden[reg] = (rsum[reg] > 0.f ? 1.f / rsum[reg] : 0.f)
                        * (float)sQv[r0 + reg];
        }
        // wave reads only its own P rows -> no barrier needed
        bf16x8 ap[4];
        #pragma unroll
        for (int kc = 0; kc < 4; ++kc)
            ap[kc] = *(const bf16x8*)(&u.P[16 * wv + l15][kc * 32 + quad * 8]);
        #pragma unroll
        for (int nt = 0; nt < 4; ++nt) {
            f32x4 a = {0.f, 0.f, 0.f, 0.f};
            #pragma unroll
            for (int kc = 0; kc < 4; ++kc) {
                int pc = (kc * 32 + quad * 8) ^ koff;
                bf16x8 bv = *(const bf16x8*)(&sVt[16 * nt + l15][pc]);
                a = __builtin_amdgcn_mfma_f32_16x16x32_bf16(ap[kc], bv, a, 0, 0, 0);
            }
            #pragma unroll
            for (int reg = 0; reg < 4; ++reg)
                out[qb + (size_t)(r0 + reg) * rowstride + 16 * nt + l15]
                    = a[reg] * rden[reg];
        }
    };

    compute_tile(0, qbase0);
    __syncthreads();   // all P/sVt/sKv/sQv reads of tile0 complete

    // ================= tile1 staging (new halves only) =================
    if (tid < 128) {
        sKv[tid] = (am[(size_t)bi * TT + jb0 * WW + tid] != 0);
    } else if (tid < 192) {
        int r = tid - 128;
        sQv[r] = (am[(size_t)bi * TT + jb1 * WW + r] != 0);
    }
    #pragma unroll
    for (int p = 0; p < 4; ++p) {
        int idx = p * 256 + tid;
        int row = idx >> 4, c4 = (idx & 15) * 4;
        uint2 w; w.x = pack2(gq[p].x, gq[p].y); w.y = pack2(gq[p].z, gq[p].w);
        *(uint2*)(&u.qk.Q[row][c4]) = w;
        uint2 wk; wk.x = pack2(gk[p].x, gk[p].y); wk.y = pack2(gk[p].z, gk[p].w);
        *(uint2*)(&u.qk.K[row][c4]) = wk;   // logical rows 64..127 -> phys 0..63
        sVt[c4 + 0][row] = f2bf(gv[p].x);   // logical keys 64..127 -> phys cols 0..63
        sVt[c4 + 1][row] = f2bf(gv[p].y);
        sVt[c4 + 2][row] = f2bf(gv[p].z);
        sVt[c4 + 3][row] = f2bf(gv[p].w);
    }
    __syncthreads();

    compute_tile(64, qbase1);
}

extern "C" void kernel_launch(void* const* d_in, const int* in_sizes, int n_in,
                              void* d_out, int out_size, void* d_ws, size_t ws_size,
                              hipStream_t stream) {
    const float* q  = (const float*)d_in[0];
    const float* k  = (const float*)d_in[1];
    const float* v  = (const float*)d_in[2];
    const int*   am = (const int*)d_in[3];
    float* out = (float*)d_out;

    const int b = in_sizes[3] / TT;   // 4
    dim3 grid(NBLK / 2, HH, b);
    dim3 block(256);
    lca_fwd<<<grid, block, 0, stream>>>(q, k, v, am, out);
}

// Round 5
// 228.950 us; speedup vs baseline: 1.0616x; 1.0616x over previous
//
#include <hip/hip_runtime.h>
#include <hip/hip_bf16.h>

// LocalCausalAttention: b=4, t=4096, h=16, d=64, window W=64.
// I/O f32, internal bf16 MFMA. One WG (4 waves) per (b, t-block, head):
//   Q[64x64] @ K[128x64]^T -> band-masked softmax -> P[64x128] @ V[128x64].
// R5: Q direct-to-fragment from global (no Q LDS) -> 36.6KB LDS -> 4 blocks/CU;
//     sched_barrier pins the batched global loads; softmax in regs pre-barrier.

#define TT 4096
#define HH 16
#define DD 64
#define WW 64
#define NBLK (TT / WW)

typedef __attribute__((ext_vector_type(8))) short bf16x8;
typedef __attribute__((ext_vector_type(4))) float f32x4;

static __device__ __forceinline__ ushort f2bf(float x) {
    return __builtin_bit_cast(unsigned short, __float2bfloat16(x));
}
static __device__ __forceinline__ uint pack2(float a, float b) {
    return (uint)f2bf(a) | ((uint)f2bf(b) << 16);
}

__global__ __launch_bounds__(256, 4)
void lca_fwd(const float* __restrict__ q, const float* __restrict__ k,
             const float* __restrict__ v, const int* __restrict__ am,
             float* __restrict__ out)
{
    const int jb = blockIdx.x;   // t-block
    const int hi = blockIdx.y;   // head
    const int bi = blockIdx.z;   // batch

    // K dead after QK^T; P overlays it (18432 >= 17408 bytes).
    __shared__ union {
        ushort K[128][72];
        ushort P[64][136];
    } u;
    __shared__ ushort sVt[64][136];   // V^T [d][key]
    __shared__ int    sKv[128];
    __shared__ int    sQv[64];

    const int tid = threadIdx.x;
    const int wv = tid >> 6, lane = tid & 63;
    const int quad = lane >> 4, l15 = lane & 15;
    const int r0 = 16 * wv + quad * 4;          // C-layout base row

    const size_t rowstride = (size_t)HH * DD;
    const size_t qbase = ((size_t)(bi * TT + jb * WW) * HH + hi) * DD;
    const long  kstart = (long)jb * WW - WW;

    // ---- issue ALL global loads up front (K, V, Q-fragments) ----
    float4 fk[8], fv[8];
    if (jb > 0) {
        #pragma unroll
        for (int p = 0; p < 8; ++p) {
            int idx = p * 256 + tid;
            int row = idx >> 4, c4 = (idx & 15) * 4;
            fk[p] = *(const float4*)(k + ((size_t)(bi * TT + kstart + row) * HH + hi) * DD + c4);
        }
        #pragma unroll
        for (int p = 0; p < 8; ++p) {
            int idx = p * 256 + tid;
            int row = idx >> 4, c4 = (idx & 15) * 4;
            fv[p] = *(const float4*)(v + ((size_t)(bi * TT + kstart + row) * HH + hi) * DD + c4);
        }
    } else {
        // jb==0: window rows 0..63 are the zero-pad block (p<4 <=> row<64)
        #pragma unroll
        for (int p = 0; p < 8; ++p) {
            float4 z = make_float4(0.f, 0.f, 0.f, 0.f);
            if (p >= 4) {
                int idx = p * 256 + tid;
                int row = idx >> 4, c4 = (idx & 15) * 4;
                z = *(const float4*)(k + ((size_t)(bi * TT + (row - 64)) * HH + hi) * DD + c4);
            }
            fk[p] = z;
        }
        #pragma unroll
        for (int p = 0; p < 8; ++p) {
            float4 z = make_float4(0.f, 0.f, 0.f, 0.f);
            if (p >= 4) {
                int idx = p * 256 + tid;
                int row = idx >> 4, c4 = (idx & 15) * 4;
                z = *(const float4*)(v + ((size_t)(bi * TT + (row - 64)) * HH + hi) * DD + c4);
            }
            fv[p] = z;
        }
    }
    // Q A-fragment loads: lane (wv,l15,quad) owns Q row 16wv+l15, cols quad*8.. / 32+quad*8..
    const float* qrow = q + qbase + (size_t)(16 * wv + l15) * rowstride + quad * 8;
    float4 q0 = *(const float4*)(qrow);
    float4 q1 = *(const float4*)(qrow + 4);
    float4 q2 = *(const float4*)(qrow + 32);
    float4 q3 = *(const float4*)(qrow + 36);

#if __has_builtin(__builtin_amdgcn_sched_barrier)
    __builtin_amdgcn_sched_barrier(0);   // don't sink/chunk the loads above
#endif

    // ---- validity ----
    if (tid < 128) {
        long tok = kstart + tid;
        sKv[tid] = (tok >= 0) && (am[(size_t)bi * TT + tok] != 0);
    } else if (tid < 192) {
        int r = tid - 128;
        sQv[r] = (am[(size_t)bi * TT + jb * WW + r] != 0);
    }

    // ---- convert + LDS staging for K and V^T ----
    #pragma unroll
    for (int p = 0; p < 8; ++p) {
        int idx = p * 256 + tid;
        int row = idx >> 4, c4 = (idx & 15) * 4;
        uint2 w; w.x = pack2(fk[p].x, fk[p].y); w.y = pack2(fk[p].z, fk[p].w);
        *(uint2*)(&u.K[row][c4]) = w;
    }
    #pragma unroll
    for (int p = 0; p < 8; ++p) {
        int idx = p * 256 + tid;
        int row = idx >> 4, c4 = (idx & 15) * 4;   // row = key, c4 = d
        sVt[c4 + 0][row] = f2bf(fv[p].x);
        sVt[c4 + 1][row] = f2bf(fv[p].y);
        sVt[c4 + 2][row] = f2bf(fv[p].z);
        sVt[c4 + 3][row] = f2bf(fv[p].w);
    }

    // build Q fragments while stores drain
    union BF8 { bf16x8 v; uint u4[4]; };
    BF8 A0, A1;
    A0.u4[0] = pack2(q0.x, q0.y); A0.u4[1] = pack2(q0.z, q0.w);
    A0.u4[2] = pack2(q1.x, q1.y); A0.u4[3] = pack2(q1.z, q1.w);
    A1.u4[0] = pack2(q2.x, q2.y); A1.u4[1] = pack2(q2.z, q2.w);
    A1.u4[2] = pack2(q3.x, q3.y); A1.u4[3] = pack2(q3.z, q3.w);

    __syncthreads();   // staging complete

    // ---- S = Q K^T : wave wv owns S rows [16wv,16wv+16) x 128 cols ----
    f32x4 acc[8];
    #pragma unroll
    for (int kt = 0; kt < 8; ++kt) {
        f32x4 a = {0.f, 0.f, 0.f, 0.f};
        bf16x8 b0 = *(const bf16x8*)(&u.K[16 * kt + l15][quad * 8]);
        bf16x8 b1 = *(const bf16x8*)(&u.K[16 * kt + l15][32 + quad * 8]);
        a = __builtin_amdgcn_mfma_f32_16x16x32_bf16(A0.v, b0, a, 0, 0, 0);
        a = __builtin_amdgcn_mfma_f32_16x16x32_bf16(A1.v, b1, a, 0, 0, 0);
        acc[kt] = a;
    }

    // ---- masked softmax, entirely in registers (pre-barrier) ----
    const float NEG = -1.0e9f;
    float rmax[4] = {NEG, NEG, NEG, NEG};
    #pragma unroll
    for (int kt = 0; kt < 8; ++kt) {
        int c = 16 * kt + l15;
        int kvc = sKv[c];
        #pragma unroll
        for (int reg = 0; reg < 4; ++reg) {
            int r = r0 + reg;
            bool valid = (c > r) && (c <= r + WW) && kvc;
            float s = valid ? acc[kt][reg] : NEG;
            acc[kt][reg] = s;
            rmax[reg] = fmaxf(rmax[reg], s);
        }
    }
    #pragma unroll
    for (int reg = 0; reg < 4; ++reg) {
        #pragma unroll
        for (int m = 1; m <= 8; m <<= 1)
            rmax[reg] = fmaxf(rmax[reg], __shfl_xor(rmax[reg], m, 64));
    }
    const float CEXP = 0.125f * 1.44269504088896f;  // scale * log2(e)
    float rsum[4] = {0.f, 0.f, 0.f, 0.f};
    #pragma unroll
    for (int kt = 0; kt < 8; ++kt) {
        #pragma unroll
        for (int reg = 0; reg < 4; ++reg) {
            float s = acc[kt][reg];
            float pex = (s > -1.0e8f) ? exp2f((s - rmax[reg]) * CEXP) : 0.f;
            rsum[reg] += pex;
            acc[kt][reg] = pex;
        }
    }
    float rden[4];
    #pragma unroll
    for (int reg = 0; reg < 4; ++reg) {
        #pragma unroll
        for (int m = 1; m <= 8; m <<= 1)
            rsum[reg] += __shfl_xor(rsum[reg], m, 64);
        rden[reg] = (rsum[reg] > 0.f ? 1.f / rsum[reg] : 0.f)
                    * (float)sQv[r0 + reg];
    }

    __syncthreads();   // all waves done reading u.K; safe to overlay u.P

    // ---- write P (bf16) ----
    #pragma unroll
    for (int kt = 0; kt < 8; ++kt) {
        int c = 16 * kt + l15;
        #pragma unroll
        for (int reg = 0; reg < 4; ++reg)
            u.P[r0 + reg][c] = f2bf(acc[kt][reg]);
    }

    // wave reads only its own P rows -> ordered by lgkmcnt, no barrier
    bf16x8 ap[4];
    #pragma unroll
    for (int kc = 0; kc < 4; ++kc)
        ap[kc] = *(const bf16x8*)(&u.P[16 * wv + l15][kc * 32 + quad * 8]);

    #pragma unroll
    for (int nt = 0; nt < 4; ++nt) {
        f32x4 a = {0.f, 0.f, 0.f, 0.f};
        #pragma unroll
        for (int kc = 0; kc < 4; ++kc) {
            bf16x8 bv = *(const bf16x8*)(&sVt[16 * nt + l15][kc * 32 + quad * 8]);
            a = __builtin_amdgcn_mfma_f32_16x16x32_bf16(ap[kc], bv, a, 0, 0, 0);
        }
        #pragma unroll
        for (int reg = 0; reg < 4; ++reg)
            out[qbase + (size_t)(r0 + reg) * rowstride + 16 * nt + l15]
                = a[reg] * rden[reg];
    }
}

extern "C" void kernel_launch(void* const* d_in, const int* in_sizes, int n_in,
                              void* d_out, int out_size, void* d_ws, size_t ws_size,
                              hipStream_t stream) {
    const float* q  = (const float*)d_in[0];
    const float* k  = (const float*)d_in[1];
    const float* v  = (const float*)d_in[2];
    const int*   am = (const int*)d_in[3];
    float* out = (float*)d_out;

    const int b = in_sizes[3] / TT;   // 4
    dim3 grid(NBLK, HH, b);
    dim3 block(256);
    lca_fwd<<<grid, block, 0, stream>>>(q, k, v, am, out);
}